// Round 5
// baseline (984.667 us; speedup 1.0000x reference)
//
#include <hip/hip_runtime.h>
#include <math.h>

// RITS recurrent model, MFMA bf16, 16-wave gate-split for 4 waves/SIMD.
// 256 blocks x 1024 threads (16 waves), block owns 16 batch rows.
// Wave pair (wp, wp+8), wp=0..7, owns jh cols [16wp,16wp+16):
//   lo wave (hi=0): gates {i,f};  hi wave: gates {g,o}   -> bfr_g = 48 VGPR
//   pointwise v-split: lo updates rows 4g+{0,1}, hi rows 4g+{2,3}
//   cross-gate 4-float exchange via LDS once per step (gxA/gxB)
// x_h: k-split partials (wv 0,1 = k 0..63; wv 8,9 = k 64..127), exchange via LDS.
// MFMA 16x16x32 lane layout: cidx=l&15 (A row / D col), gidx=l>>4 (k-group of 8);
// D: row=4*gidx+v, col=cidx [m89-verified].
// Per-step: A(flush+panel h) bar1 B(gates s0-3 + xh) bar2 B2(xc, 2 waves) bar3
//           [imp/loss off-path] C(gates s4,5 + gamma + exchange) bar4 D(pointwise)

#define T_LEN 252
#define FEAT  21
#define HID   128
#define BTOT  4096
#define BT    16
#define NB    (BTOT / BT)   // 256
#define NTHR  1024
#define LOG2E 1.44269504088896f

// ws layout (floats)
#define WS_RDEN   0      // [256] (252 used)
#define WS_XL     256    // [256]
#define WS_YNUM   512    // [256]
#define WS_YDEN   768    // [256]

typedef __attribute__((ext_vector_type(8))) short s16x8;
typedef __attribute__((ext_vector_type(4))) float f32x4;

#define MFMA16(A, B, C) __builtin_amdgcn_mfma_f32_16x16x32_bf16((A), (B), (C), 0, 0, 0)

__device__ __forceinline__ float sigmoid_f(float x) { return 1.0f / (1.0f + __expf(-x)); }
__device__ __forceinline__ float tanh_f(float x) {
    return 2.0f / (1.0f + __expf(-2.0f * x)) - 1.0f;
}
__device__ __forceinline__ float exp2_f(float x) { return __builtin_amdgcn_exp2f(x); }
__device__ __forceinline__ unsigned short to_bf16(float x) {   // RNE (setup only)
    unsigned int u = __float_as_uint(x);
    return (unsigned short)((u + 0x7FFFu + ((u >> 16) & 1u)) >> 16);
}
__device__ __forceinline__ unsigned short to_bf16f(float x) {  // round-half-up, 2 ops
    return (unsigned short)((__float_as_uint(x) + 0x8000u) >> 16);
}

// ---- pre-pass: rden[t] = 1 / (sum_{b,f} masks[b][t][f] + 1e-5) ----
__global__ __launch_bounds__(1024) void rits_den(
    const float* __restrict__ masks, float* __restrict__ rden)
{
    const int t = blockIdx.x;
    const int tid = threadIdx.x;
    __shared__ float red[1024];
    float acc = 0.0f;
    if (tid < 48 * FEAT) {                     // 1008 active
        int r0 = tid / FEAT, f = tid - r0 * FEAT;
        for (int r = r0; r < BTOT; r += 48)
            acc += masks[r * (T_LEN * FEAT) + t * FEAT + f];
    }
    red[tid] = acc;
    __syncthreads();
    #pragma unroll
    for (int s = 512; s > 0; s >>= 1) {
        if (tid < s) red[tid] += red[tid + s];
        __syncthreads();
    }
    if (tid == 0) rden[t] = 1.0f / (red[0] + 1e-5f);
}

__global__ __launch_bounds__(NTHR, 4) void rits_main(
    const float* __restrict__ values, const float* __restrict__ masks,
    const float* __restrict__ deltas,
    const float* __restrict__ labels, const float* __restrict__ is_train,
    const float* __restrict__ W_decay, const float* __restrict__ b_decay,
    const float* __restrict__ W_reg, const float* __restrict__ b_reg,
    const float* __restrict__ W_ih, const float* __restrict__ W_hh,
    const float* __restrict__ b_ih, const float* __restrict__ b_hh,
    const float* __restrict__ W_out, const float* __restrict__ b_out,
    const float* __restrict__ rden,
    float* __restrict__ out_yh,     // [BTOT]
    float* __restrict__ out_imp,    // [BTOT][T][FEAT]
    float* __restrict__ xlpart, float* __restrict__ wsynum, float* __restrict__ wsyden)
{
    const int tid  = threadIdx.x;
    const int blk  = blockIdx.x;
    const int bbase = blk * BT;
    const int l    = tid & 63;
    const int wv   = tid >> 6;          // 0..15
    const int wp   = wv & 7;            // wave-pair index
    const int hi   = wv >> 3;           // 0: gates i,f ; 1: gates g,o
    const int cidx = l & 15;
    const int gidx = l >> 4;
    const int jh   = 16 * wp + cidx;    // owned hidden column

    // A-panel: k 0..127 decayed h; 128+2f = x_c[f], 128+2f+1 = m[f]; rest 0.
    __shared__ unsigned short ak_s[2][BT][200];
    __shared__ unsigned short d_s[2][BT][40];     // bf16 deltas (x LOG2E NOT applied)
    __shared__ float2 xm_s[2][BT][22];            // (x, m) fp32
    __shared__ float xhp_s[2][64][4];             // x_h k-high partials
    __shared__ float gxA_s[8][64][4];             // lo->hi: {i2,i3,f2,f3}
    __shared__ float gxB_s[8][64][4];             // hi->lo: {g0,g1,o0,o1}
    __shared__ float hfin_s[BT][HID + 4];
    __shared__ float rden_s[T_LEN];
    __shared__ float red_s[NTHR];

    for (int i = tid; i < 2 * BT * 200; i += NTHR) ((unsigned short*)ak_s)[i] = 0;
    for (int i = tid; i < 2 * BT * 40;  i += NTHR) ((unsigned short*)d_s)[i] = 0;
    if (tid < T_LEN) rden_s[tid] = rden[tid];

    // ---------- one-time B-fragments (bf16) ----------
    // gates: K = [h(128) | interleaved xc,m (42) | pad->192]; own gates 2*hi+q
    s16x8 bfr_g[2][6];
    #pragma unroll
    for (int q = 0; q < 2; ++q) {
        const int gq = 2 * hi + q;
        const float* rhh = W_hh + (gq * HID + jh) * HID;
        const float* rih = W_ih + (gq * HID + jh) * (2 * FEAT);
        #pragma unroll
        for (int s = 0; s < 6; ++s) {
            s16x8 fr;
            #pragma unroll
            for (int j = 0; j < 8; ++j) {
                int k = 32 * s + 8 * gidx + j;
                float wq;
                if (k < HID) wq = rhh[k];
                else {
                    int kk = k - HID, f2 = kk >> 1, sel = kk & 1;
                    wq = (f2 < FEAT) ? (sel ? rih[FEAT + f2] : rih[f2]) : 0.0f;
                }
                fr[j] = (short)to_bf16(wq);
            }
            bfr_g[q][s] = fr;
        }
    }
    // gamma weights pre-scaled by log2(e) -> exp2 path
    s16x8 bfr_d;
    {
        const float* rw = W_decay + jh * FEAT;
        #pragma unroll
        for (int j = 0; j < 8; ++j) {
            int f = 8 * gidx + j;
            bfr_d[j] = (short)to_bf16(f < FEAT ? rw[f] * LOG2E : 0.0f);
        }
    }
    const float bd_r = b_decay[jh] * LOG2E;
    // x_h k-split partial weights: wv 0,1 k 0..63 ; wv 8,9 k 64..127
    const int  fx      = 16 * wp + cidx;
    const bool xh_wave = (wp < 2);
    const bool fxv     = xh_wave && (fx < FEAT);
    s16x8 bfr_x[2];
    #pragma unroll
    for (int s2 = 0; s2 < 2; ++s2) {
        int s = 2 * hi + s2;
        s16x8 fr;
        #pragma unroll
        for (int j = 0; j < 8; ++j) {
            int k = 32 * s + 8 * gidx + j;
            fr[j] = (short)to_bf16(fxv ? W_reg[fx * HID + k] : 0.0f);
        }
        bfr_x[s2] = fr;
    }
    const float br_r = (fxv && !hi) ? b_reg[fx] : 0.0f;
    float bs_r[2];
    #pragma unroll
    for (int q = 0; q < 2; ++q) {
        int gq = 2 * hi + q;
        bs_r[q] = b_ih[gq * HID + jh] + b_hh[gq * HID + jh];
    }

    // ---------- prologue staging ----------
    const int rr = tid / FEAT, ff = tid - rr * FEAT;   // active for tid < 336
    const int rowbase = (bbase + rr) * (T_LEN * FEAT) + ff;
    float nx = 0.f, nm = 0.f, nd = 0.f;
    if (tid < BT * FEAT) {
        xm_s[0][rr][ff] = make_float2(values[rowbase], masks[rowbase]);
        nx = values[rowbase + FEAT];
        nm = masks[rowbase + FEAT];
        nd = deltas[rowbase + FEAT];
    }
    const int ibase = (bbase + 4 * gidx) * (T_LEN * FEAT) + fx;  // imp store base (b2 lanes)
    float c_r[2]  = {0.f, 0.f};
    float h_r[2]  = {0.f, 0.f};
    float gam_r[2] = {0.f, 0.f};       // h=0 at t=0 -> value irrelevant
    float xl_acc = 0.0f;
    __syncthreads();

    const bool b2w = xh_wave && !hi;   // wv 0,1

    for (int t = 0; t < T_LEN; ++t) {
        const int par = t & 1;

        // ---- A: flush t+1 stages, issue t+2 loads, panel h write ----
        const float rd = rden_s[t];
        if (tid < BT * FEAT) {
            d_s[par ^ 1][rr][ff] = to_bf16f(nd);
            xm_s[par ^ 1][rr][ff] = make_float2(nx, nm);
            int idx = (t + 2 < T_LEN) ? (t + 2) : (T_LEN - 1);
            int o = rowbase + idx * FEAT;
            nx = values[o]; nm = masks[o]; nd = deltas[o];
        }
        #pragma unroll
        for (int u = 0; u < 2; ++u)
            ak_s[par][4 * gidx + 2 * hi + u][jh] = to_bf16f(h_r[u] * gam_r[u]);
        __syncthreads();                               // bar1

        // ---- B: gate MFMAs s0..3 + x_h partials ----
        s16x8 aF0 = *(const s16x8*)&ak_s[par][cidx][      8 * gidx];
        s16x8 aF1 = *(const s16x8*)&ak_s[par][cidx][ 32 + 8 * gidx];
        s16x8 aF2 = *(const s16x8*)&ak_s[par][cidx][ 64 + 8 * gidx];
        s16x8 aF3 = *(const s16x8*)&ak_s[par][cidx][ 96 + 8 * gidx];
        f32x4 acc0 = {bs_r[0], bs_r[0], bs_r[0], bs_r[0]};
        f32x4 acc1 = {bs_r[1], bs_r[1], bs_r[1], bs_r[1]};
        acc0 = MFMA16(aF0, bfr_g[0][0], acc0); acc1 = MFMA16(aF0, bfr_g[1][0], acc1);
        acc0 = MFMA16(aF1, bfr_g[0][1], acc0); acc1 = MFMA16(aF1, bfr_g[1][1], acc1);
        acc0 = MFMA16(aF2, bfr_g[0][2], acc0); acc1 = MFMA16(aF2, bfr_g[1][2], acc1);
        acc0 = MFMA16(aF3, bfr_g[0][3], acc0); acc1 = MFMA16(aF3, bfr_g[1][3], acc1);
        f32x4 xacc = {0.f, 0.f, 0.f, 0.f};
        if (xh_wave) {
            s16x8 xa0 = hi ? aF2 : aF0;
            s16x8 xa1 = hi ? aF3 : aF1;
            xacc = MFMA16(xa0, bfr_x[0], xacc);
            xacc = MFMA16(xa1, bfr_x[1], xacc);
            if (hi) *(f32x4*)&xhp_s[wp][l][0] = xacc;
        }
        __syncthreads();                               // bar2

        // ---- B2 (wv 0,1): x_h finalize, x_c, panel write ----
        float sxh[4], sxc[4], sxv[4], smv[4];
        bool b2 = b2w && (fx < FEAT);
        if (b2) {
            f32x4 part = *(const f32x4*)&xhp_s[wp][l][0];
            #pragma unroll
            for (int v = 0; v < 4; ++v) {
                float xh = xacc[v] + part[v] + br_r;
                float2 xm = xm_s[par][4 * gidx + v][fx];
                float xc = xm.y * xm.x + (1.0f - xm.y) * xh;
                unsigned int pk = ((unsigned int)to_bf16f(xm.y) << 16)
                                | (unsigned int)to_bf16f(xc);
                *(unsigned int*)&ak_s[par][4 * gidx + v][HID + 2 * fx] = pk;
                sxh[v] = xh; sxc[v] = xc; sxv[v] = xm.x; smv[v] = xm.y;
            }
        }
        __syncthreads();                               // bar3

        // off-critical-path: imputation store + loss accumulate
        if (b2) {
            #pragma unroll
            for (int v = 0; v < 4; ++v) {
                out_imp[ibase + v * (T_LEN * FEAT) + t * FEAT] = sxc[v];
                xl_acc += fabsf(sxv[v] - sxh[v]) * smv[v] * rd;
            }
        }

        // ---- C: gate MFMAs s4,5 + gamma + exchange write ----
        s16x8 a4 = *(const s16x8*)&ak_s[par][cidx][128 + 8 * gidx];
        s16x8 a5 = *(const s16x8*)&ak_s[par][cidx][160 + 8 * gidx];
        s16x8 ad = *(const s16x8*)&d_s[par ^ 1][cidx][8 * gidx];
        acc0 = MFMA16(a4, bfr_g[0][4], acc0); acc0 = MFMA16(a5, bfr_g[0][5], acc0);
        acc1 = MFMA16(a4, bfr_g[1][4], acc1); acc1 = MFMA16(a5, bfr_g[1][5], acc1);
        f32x4 gacc = {bd_r, bd_r, bd_r, bd_r};
        gacc = MFMA16(ad, bfr_d, gacc);
        if (!hi) {
            f32x4 e = {acc0[2], acc0[3], acc1[2], acc1[3]};   // i,f for v=2,3
            *(f32x4*)&gxA_s[wp][l][0] = e;
        } else {
            f32x4 e = {acc0[0], acc0[1], acc1[0], acc1[1]};   // g,o for v=0,1
            *(f32x4*)&gxB_s[wp][l][0] = e;
        }
        __syncthreads();                               // bar4

        // ---- D: pointwise for own 2 rows ----
        f32x4 p = hi ? *(const f32x4*)&gxA_s[wp][l][0]
                     : *(const f32x4*)&gxB_s[wp][l][0];
        #pragma unroll
        for (int u = 0; u < 2; ++u) {
            int v = 2 * hi + u;
            float iv, fv, gv, ov;
            if (!hi) { iv = acc0[u]; fv = acc1[u]; gv = p[u]; ov = p[2 + u]; }
            else     { iv = p[u]; fv = p[2 + u]; gv = acc0[v]; ov = acc1[v]; }
            float ig = sigmoid_f(iv);
            float fg = sigmoid_f(fv);
            float gg = tanh_f(gv);
            float og = sigmoid_f(ov);
            c_r[u] = fg * c_r[u] + ig * gg;
            h_r[u] = og * tanh_f(c_r[u]);
            gam_r[u] = exp2_f(-fmaxf(gacc[v], 0.0f));
        }
        // no barrier: next A writes panel[par^1] / d_s[par] / xm_s[par^1],
        // all barrier-separated from this step's readers.
    }

    // ---------- epilogue ----------
    #pragma unroll
    for (int u = 0; u < 2; ++u)
        hfin_s[4 * gidx + 2 * hi + u][jh] = h_r[u];
    red_s[tid] = xl_acc;
    __syncthreads();
    #pragma unroll
    for (int s = NTHR / 2; s > 0; s >>= 1) {
        if (tid < s) red_s[tid] += red_s[tid + s];
        __syncthreads();
    }
    if (tid == 0) xlpart[blk] = red_s[0];

    float yerr = 0.0f, ytr = 0.0f;
    if (tid < BT) {
        float acc = b_out[0];
        for (int k = 0; k < HID; ++k) acc += W_out[k] * hfin_s[tid][k];
        out_yh[bbase + tid] = acc;
        float it = is_train[bbase + tid];
        float dv = acc - labels[bbase + tid];
        yerr = dv * dv * it;
        ytr  = it;
    }
    #pragma unroll
    for (int s = 8; s > 0; s >>= 1) {
        yerr += __shfl_down(yerr, s);
        ytr  += __shfl_down(ytr, s);
    }
    if (tid == 0) { wsynum[blk] = yerr; wsyden[blk] = ytr; }
}

__global__ __launch_bounds__(256) void rits_final(
    const float* __restrict__ xlpart,
    const float* __restrict__ wsynum, const float* __restrict__ wsyden,
    float* __restrict__ d_out)
{
    __shared__ float sx[256], sy[256], sz[256];
    int tid = threadIdx.x;
    sx[tid] = xlpart[tid];
    sy[tid] = wsynum[tid];
    sz[tid] = wsyden[tid];
    __syncthreads();
    for (int s = 128; s > 0; s >>= 1) {
        if (tid < s) { sx[tid] += sx[tid + s]; sy[tid] += sy[tid + s]; sz[tid] += sz[tid + s]; }
        __syncthreads();
    }
    if (tid == 0) d_out[0] = sx[0] + sy[0] / (sz[0] + 1e-5f);
}

extern "C" void kernel_launch(void* const* d_in, const int* in_sizes, int n_in,
                              void* d_out, int out_size, void* d_ws, size_t ws_size,
                              hipStream_t stream)
{
    const float* values    = (const float*)d_in[0];
    const float* masks     = (const float*)d_in[1];
    const float* deltas    = (const float*)d_in[2];
    // d_in[3] evals, d_in[4] eval_masks : unused
    const float* labels    = (const float*)d_in[5];
    const float* is_train  = (const float*)d_in[6];
    const float* W_decay   = (const float*)d_in[7];
    const float* b_decay   = (const float*)d_in[8];
    const float* W_reg     = (const float*)d_in[9];
    const float* b_reg     = (const float*)d_in[10];
    const float* W_ih      = (const float*)d_in[11];
    const float* W_hh      = (const float*)d_in[12];
    const float* b_ih      = (const float*)d_in[13];
    const float* b_hh      = (const float*)d_in[14];
    const float* W_out     = (const float*)d_in[15];
    const float* b_out     = (const float*)d_in[16];

    float* ws     = (float*)d_ws;
    float* rden   = ws + WS_RDEN;
    float* xlpart = ws + WS_XL;
    float* wsynum = ws + WS_YNUM;
    float* wsyden = ws + WS_YDEN;

    float* out     = (float*)d_out;
    float* out_yh  = out + 1;
    float* out_imp = out + 1 + BTOT;

    rits_den<<<dim3(T_LEN), dim3(1024), 0, stream>>>(masks, rden);

    rits_main<<<dim3(NB), dim3(NTHR), 0, stream>>>(
        values, masks, deltas, labels, is_train,
        W_decay, b_decay, W_reg, b_reg, W_ih, W_hh, b_ih, b_hh, W_out, b_out,
        rden, out_yh, out_imp, xlpart, wsynum, wsyden);

    rits_final<<<dim3(1), dim3(256), 0, stream>>>(xlpart, wsynum, wsyden, out);
}

// Round 6
// 422.496 us; speedup vs baseline: 2.3306x; 2.3306x over previous
//
#include <hip/hip_runtime.h>
#include <math.h>

// RITS recurrent model, MFMA bf16, 2-barrier step via weight folding.
// 256 blocks x 512 threads (8 waves), block owns 16 batch rows.
// Fold: Whh2 = W_hh + W_ih_x @ W_reg  (rits_fold pre-kernel);
//       bias += W_ih_x @ b_reg; gates = Whh2@h_d + W_ih_x@e + W_ih_m@m + b,
//       e = m*(x - x_h). Only e is on the post-x_h critical path.
// Panel ak_s[par][row][k]: k 0..127 h_d, 128..159 e (f=k-128, pad 0),
//       160..191 m (f=k-160, pad 0). Stride 200 shorts (2-way bank = free).
// Step t (par=t&1), 2 barriers:
//   P: stg flush d(t+1),x/m(t+1)->[par^1]; issue loads t+2; h_d(t)->panel[par]
//   bar1
//   Q: all: 16 gate-h MFMAs + 4 m-MFMAs + gamma(t+1) MFMA;
//      waves 0,1: 4 xh MFMAs -> e -> panel[par], imp store, loss acc;
//      stg: m(t+1)->panel[par^1] m-section; reg shift
//   bar2
//   R: read e-frag; 4 e-MFMAs; pointwise (exp2/rcp, prescaled); gamma exp2
// Race audit: every buffer's write->read and read->rewrite pairs are
// barrier-separated (h:[P,bar1,Q]; e:[Q,bar2,R]; m:[Q(t-1),bar,R(t)],
// rewrite Q(t+2) after bar1(t+2); d:[P,bar1,Q]; xm:[P,bar1,Q(t+1)]).

#define T_LEN 252
#define FEAT  21
#define HID   128
#define BTOT  4096
#define BT    16
#define NB    (BTOT / BT)   // 256
#define NTHR  512
#define LOG2E 1.44269504088896f

// ws layout (floats)
#define WS_WHH2   0        // [512][128] folded recurrent weight
#define WS_RDEN   65536    // [256] (252 used)
#define WS_XL     65792    // [256]
#define WS_YNUM   66048    // [256]
#define WS_YDEN   66304    // [256]

typedef __attribute__((ext_vector_type(8))) short s16x8;
typedef __attribute__((ext_vector_type(4))) float f32x4;

#define MFMA16(A, B, C) __builtin_amdgcn_mfma_f32_16x16x32_bf16((A), (B), (C), 0, 0, 0)

__device__ __forceinline__ float exp2_f(float x) { return __builtin_amdgcn_exp2f(x); }
__device__ __forceinline__ float rcp_f(float x)  { return __builtin_amdgcn_rcpf(x); }
__device__ __forceinline__ unsigned short to_bf16(float x) {   // RNE (setup only)
    unsigned int u = __float_as_uint(x);
    return (unsigned short)((u + 0x7FFFu + ((u >> 16) & 1u)) >> 16);
}
__device__ __forceinline__ unsigned short to_bf16f(float x) {  // round-half-up, 2 ops
    return (unsigned short)((__float_as_uint(x) + 0x8000u) >> 16);
}

// ---- pre-pass 1: rden[t] = 1 / (sum_{b,f} masks[b][t][f] + 1e-5) ----
__global__ __launch_bounds__(1024) void rits_den(
    const float* __restrict__ masks, float* __restrict__ rden)
{
    const int t = blockIdx.x;
    const int tid = threadIdx.x;
    __shared__ float red[1024];
    float acc = 0.0f;
    if (tid < 48 * FEAT) {
        int r0 = tid / FEAT, f = tid - r0 * FEAT;
        for (int r = r0; r < BTOT; r += 48)
            acc += masks[r * (T_LEN * FEAT) + t * FEAT + f];
    }
    red[tid] = acc;
    __syncthreads();
    #pragma unroll
    for (int s = 512; s > 0; s >>= 1) {
        if (tid < s) red[tid] += red[tid + s];
        __syncthreads();
    }
    if (tid == 0) rden[t] = 1.0f / (red[0] + 1e-5f);
}

// ---- pre-pass 2: Whh2 = W_hh + W_ih[:, :FEAT] @ W_reg  (fp32) ----
__global__ __launch_bounds__(256) void rits_fold(
    const float* __restrict__ W_ih, const float* __restrict__ W_hh,
    const float* __restrict__ W_reg, float* __restrict__ whh2)
{
    int idx = blockIdx.x * 256 + threadIdx.x;       // 0..65535
    int j4 = idx >> 7, k = idx & (HID - 1);
    float acc = W_hh[j4 * HID + k];
    #pragma unroll
    for (int f = 0; f < FEAT; ++f)
        acc += W_ih[j4 * (2 * FEAT) + f] * W_reg[f * HID + k];
    whh2[idx] = acc;
}

__global__ __launch_bounds__(NTHR, 2) void rits_main(
    const float* __restrict__ values, const float* __restrict__ masks,
    const float* __restrict__ deltas,
    const float* __restrict__ labels, const float* __restrict__ is_train,
    const float* __restrict__ W_decay, const float* __restrict__ b_decay,
    const float* __restrict__ W_reg, const float* __restrict__ b_reg,
    const float* __restrict__ W_ih, const float* __restrict__ W_hh,
    const float* __restrict__ b_ih, const float* __restrict__ b_hh,
    const float* __restrict__ W_out, const float* __restrict__ b_out,
    const float* __restrict__ whh2, const float* __restrict__ rden,
    float* __restrict__ out_yh,     // [BTOT]
    float* __restrict__ out_imp,    // [BTOT][T][FEAT]
    float* __restrict__ xlpart, float* __restrict__ wsynum, float* __restrict__ wsyden)
{
    const int tid  = threadIdx.x;
    const int blk  = blockIdx.x;
    const int bbase = blk * BT;
    const int l    = tid & 63;
    const int wv   = tid >> 6;          // wave 0..7
    const int cidx = l & 15;
    const int gidx = l >> 4;            // k-group 0..3
    const int jh   = 16 * wv + cidx;    // owned hidden column

    __shared__ unsigned short ak_s[2][BT][200];
    __shared__ unsigned short d_s[2][BT][40];     // bf16 deltas, cols 21..39 zero
    __shared__ float2 xm_s[2][BT][22];            // (x, m) fp32
    __shared__ float hfin_s[BT][HID + 4];
    __shared__ float rden_s[T_LEN];
    __shared__ float red_s[NTHR];

    for (int i = tid; i < 2 * BT * 200; i += NTHR) ((unsigned short*)ak_s)[i] = 0;
    for (int i = tid; i < 2 * BT * 40;  i += NTHR) ((unsigned short*)d_s)[i] = 0;
    if (tid < T_LEN) rden_s[tid] = rden[tid];

    // ---------- one-time B-fragments (bf16), gate weights prescaled ----------
    // s=0..3: Whh2 (k 0..127); s=4: W_ih x-part (e); s=5: W_ih m-part (m)
    s16x8 bfr_g[4][6];
    float bs_r[4];
    #pragma unroll
    for (int g = 0; g < 4; ++g) {
        const float sg = (g == 2) ? (2.0f * LOG2E) : LOG2E;
        const float* rh2 = whh2 + (g * HID + jh) * HID;
        const float* rih = W_ih + (g * HID + jh) * (2 * FEAT);
        #pragma unroll
        for (int s = 0; s < 6; ++s) {
            s16x8 fr;
            #pragma unroll
            for (int j = 0; j < 8; ++j) {
                int k = 32 * s + 8 * gidx + j;
                float w;
                if (k < HID)       w = rh2[k];
                else if (k < 160)  w = (k - 128 < FEAT) ? rih[k - 128] : 0.0f;
                else               w = (k - 160 < FEAT) ? rih[FEAT + (k - 160)] : 0.0f;
                fr[j] = (short)to_bf16(w * sg);
            }
            bfr_g[g][s] = fr;
        }
        float bb = b_ih[g * HID + jh] + b_hh[g * HID + jh];
        #pragma unroll
        for (int f = 0; f < FEAT; ++f) bb += rih[f] * b_reg[f];   // fold b_reg
        bs_r[g] = bb * sg;
    }
    s16x8 bfr_d;
    {
        const float* rw = W_decay + jh * FEAT;
        #pragma unroll
        for (int j = 0; j < 8; ++j) {
            int f = 8 * gidx + j;
            bfr_d[j] = (short)to_bf16(f < FEAT ? rw[f] * LOG2E : 0.0f);
        }
    }
    const float bd_r = b_decay[jh] * LOG2E;
    // x_h weights (waves 0,1 own output col f = 16wv+cidx), NOT prescaled
    const int  fx  = 16 * wv + cidx;
    const bool fxv = (wv < 2) && (fx < FEAT);
    const int  fxc = fxv ? fx : 0;
    s16x8 bfr_r[4];
    #pragma unroll
    for (int s = 0; s < 4; ++s) {
        s16x8 fr;
        #pragma unroll
        for (int j = 0; j < 8; ++j) {
            int k = 32 * s + 8 * gidx + j;
            fr[j] = (short)to_bf16(fxv ? W_reg[fxc * HID + k] : 0.0f);
        }
        bfr_r[s] = fr;
    }
    const float br_r = fxv ? b_reg[fxc] : 0.0f;
    __syncthreads();   // zero-init visible before prologue panel writes

    // ---------- prologue: staging on waves 2..7 ----------
    const int st  = tid - 128;
    const bool stg = (st >= 0) && (st < BT * FEAT);
    const int rr = stg ? st / FEAT : 0;
    const int ff = stg ? (st - rr * FEAT) : 0;
    const int rowbase = (bbase + rr) * (T_LEN * FEAT) + ff;
    float nx = 0.f, nm = 0.f, nd = 0.f;
    if (stg) {
        float x0 = values[rowbase], m0 = masks[rowbase];
        xm_s[0][rr][ff] = make_float2(x0, m0);
        ak_s[0][rr][160 + ff] = to_bf16(m0);            // m(0) -> panel[0]
        nx = values[rowbase + FEAT];
        nm = masks[rowbase + FEAT];
        nd = deltas[rowbase + FEAT];
    }
    const int ibase = (bbase + 4 * gidx) * (T_LEN * FEAT) + fxc;
    float c_r[4]   = {0.f, 0.f, 0.f, 0.f};
    float h_r[4]   = {0.f, 0.f, 0.f, 0.f};
    float gam_r[4] = {0.f, 0.f, 0.f, 0.f};   // h=0 at t=0 -> value irrelevant
    float xl_acc = 0.0f;
    __syncthreads();

    for (int t = 0; t < T_LEN; ++t) {
        const int par = t & 1;

        // ---- P: flush t+1 stages, issue t+2 loads, h_d -> panel[par] ----
        float lx = 0.f, lm = 0.f, ld = 0.f;
        if (stg) {
            d_s[par ^ 1][rr][ff] = to_bf16f(nd);
            xm_s[par ^ 1][rr][ff] = make_float2(nx, nm);
            int idx = (t + 2 < T_LEN) ? (t + 2) : (T_LEN - 1);
            int o = rowbase + idx * FEAT;
            lx = values[o]; lm = masks[o]; ld = deltas[o];
        }
        #pragma unroll
        for (int v = 0; v < 4; ++v)
            ak_s[par][4 * gidx + v][jh] = to_bf16f(h_r[v] * gam_r[v]);
        __syncthreads();                               // bar1

        // ---- Q: gate-h + m + gamma MFMAs; waves 0,1: xh -> e ----
        s16x8 aF0 = *(const s16x8*)&ak_s[par][cidx][      8 * gidx];
        s16x8 aF1 = *(const s16x8*)&ak_s[par][cidx][ 32 + 8 * gidx];
        s16x8 aF2 = *(const s16x8*)&ak_s[par][cidx][ 64 + 8 * gidx];
        s16x8 aF3 = *(const s16x8*)&ak_s[par][cidx][ 96 + 8 * gidx];
        s16x8 aM  = *(const s16x8*)&ak_s[par][cidx][160 + 8 * gidx];
        s16x8 ad  = *(const s16x8*)&d_s[par ^ 1][cidx][8 * gidx];
        if (stg) ak_s[par ^ 1][rr][160 + ff] = to_bf16f(nm);   // m(t+1)

        f32x4 acc0 = {bs_r[0], bs_r[0], bs_r[0], bs_r[0]};
        f32x4 acc1 = {bs_r[1], bs_r[1], bs_r[1], bs_r[1]};
        f32x4 acc2 = {bs_r[2], bs_r[2], bs_r[2], bs_r[2]};
        f32x4 acc3 = {bs_r[3], bs_r[3], bs_r[3], bs_r[3]};
        acc0 = MFMA16(aF0, bfr_g[0][0], acc0); acc1 = MFMA16(aF0, bfr_g[1][0], acc1);
        acc2 = MFMA16(aF0, bfr_g[2][0], acc2); acc3 = MFMA16(aF0, bfr_g[3][0], acc3);
        acc0 = MFMA16(aF1, bfr_g[0][1], acc0); acc1 = MFMA16(aF1, bfr_g[1][1], acc1);
        acc2 = MFMA16(aF1, bfr_g[2][1], acc2); acc3 = MFMA16(aF1, bfr_g[3][1], acc3);
        acc0 = MFMA16(aF2, bfr_g[0][2], acc0); acc1 = MFMA16(aF2, bfr_g[1][2], acc1);
        acc2 = MFMA16(aF2, bfr_g[2][2], acc2); acc3 = MFMA16(aF2, bfr_g[3][2], acc3);
        acc0 = MFMA16(aF3, bfr_g[0][3], acc0); acc1 = MFMA16(aF3, bfr_g[1][3], acc1);
        acc2 = MFMA16(aF3, bfr_g[2][3], acc2); acc3 = MFMA16(aF3, bfr_g[3][3], acc3);
        acc0 = MFMA16(aM, bfr_g[0][5], acc0);  acc1 = MFMA16(aM, bfr_g[1][5], acc1);
        acc2 = MFMA16(aM, bfr_g[2][5], acc2);  acc3 = MFMA16(aM, bfr_g[3][5], acc3);
        f32x4 gacc = {bd_r, bd_r, bd_r, bd_r};
        gacc = MFMA16(ad, bfr_d, gacc);

        if (wv < 2) {
            f32x4 xacc = {br_r, br_r, br_r, br_r};
            xacc = MFMA16(aF0, bfr_r[0], xacc);
            xacc = MFMA16(aF1, bfr_r[1], xacc);
            xacc = MFMA16(aF2, bfr_r[2], xacc);
            xacc = MFMA16(aF3, bfr_r[3], xacc);
            if (fxv) {
                const float rd = rden_s[t];
                #pragma unroll
                for (int v = 0; v < 4; ++v) {
                    float2 xm = xm_s[par][4 * gidx + v][fxc];
                    float xh = xacc[v];
                    float e  = xm.y * (xm.x - xh);
                    ak_s[par][4 * gidx + v][128 + fxc] = to_bf16f(e);
                    out_imp[ibase + v * (T_LEN * FEAT) + t * FEAT] = xh + e;
                    xl_acc += fabsf(xm.x - xh) * xm.y * rd;
                }
            }
        }
        if (stg) { nx = lx; nm = lm; nd = ld; }
        __syncthreads();                               // bar2

        // ---- R: e-MFMAs + pointwise ----
        s16x8 aE = *(const s16x8*)&ak_s[par][cidx][128 + 8 * gidx];
        acc0 = MFMA16(aE, bfr_g[0][4], acc0);
        acc1 = MFMA16(aE, bfr_g[1][4], acc1);
        acc2 = MFMA16(aE, bfr_g[2][4], acc2);
        acc3 = MFMA16(aE, bfr_g[3][4], acc3);
        #pragma unroll
        for (int v = 0; v < 4; ++v) {
            float ig = rcp_f(1.0f + exp2_f(-acc0[v]));
            float fg = rcp_f(1.0f + exp2_f(-acc1[v]));
            float gg = 2.0f * rcp_f(1.0f + exp2_f(-acc2[v])) - 1.0f;
            float og = rcp_f(1.0f + exp2_f(-acc3[v]));
            c_r[v] = fg * c_r[v] + ig * gg;
            float th = 2.0f * rcp_f(1.0f + exp2_f(-2.0f * LOG2E * c_r[v])) - 1.0f;
            h_r[v] = og * th;
            gam_r[v] = exp2_f(-fmaxf(gacc[v], 0.0f));
        }
        // no barrier: P(t+1) writes are disjoint or barrier-separated (audit above)
    }

    // ---------- epilogue ----------
    #pragma unroll
    for (int v = 0; v < 4; ++v) hfin_s[4 * gidx + v][jh] = h_r[v];
    red_s[tid] = xl_acc;
    __syncthreads();
    #pragma unroll
    for (int s = NTHR / 2; s > 0; s >>= 1) {
        if (tid < s) red_s[tid] += red_s[tid + s];
        __syncthreads();
    }
    if (tid == 0) xlpart[blk] = red_s[0];

    float yerr = 0.0f, ytr = 0.0f;
    if (tid < BT) {
        float acc = b_out[0];
        for (int k = 0; k < HID; ++k) acc += W_out[k] * hfin_s[tid][k];
        out_yh[bbase + tid] = acc;
        float it = is_train[bbase + tid];
        float dv = acc - labels[bbase + tid];
        yerr = dv * dv * it;
        ytr  = it;
    }
    #pragma unroll
    for (int s = 8; s > 0; s >>= 1) {
        yerr += __shfl_down(yerr, s);
        ytr  += __shfl_down(ytr, s);
    }
    if (tid == 0) { wsynum[blk] = yerr; wsyden[blk] = ytr; }
}

__global__ __launch_bounds__(256) void rits_final(
    const float* __restrict__ xlpart,
    const float* __restrict__ wsynum, const float* __restrict__ wsyden,
    float* __restrict__ d_out)
{
    __shared__ float sx[256], sy[256], sz[256];
    int tid = threadIdx.x;
    sx[tid] = xlpart[tid];
    sy[tid] = wsynum[tid];
    sz[tid] = wsyden[tid];
    __syncthreads();
    for (int s = 128; s > 0; s >>= 1) {
        if (tid < s) { sx[tid] += sx[tid + s]; sy[tid] += sy[tid + s]; sz[tid] += sz[tid + s]; }
        __syncthreads();
    }
    if (tid == 0) d_out[0] = sx[0] + sy[0] / (sz[0] + 1e-5f);
}

extern "C" void kernel_launch(void* const* d_in, const int* in_sizes, int n_in,
                              void* d_out, int out_size, void* d_ws, size_t ws_size,
                              hipStream_t stream)
{
    const float* values    = (const float*)d_in[0];
    const float* masks     = (const float*)d_in[1];
    const float* deltas    = (const float*)d_in[2];
    // d_in[3] evals, d_in[4] eval_masks : unused
    const float* labels    = (const float*)d_in[5];
    const float* is_train  = (const float*)d_in[6];
    const float* W_decay   = (const float*)d_in[7];
    const float* b_decay   = (const float*)d_in[8];
    const float* W_reg     = (const float*)d_in[9];
    const float* b_reg     = (const float*)d_in[10];
    const float* W_ih      = (const float*)d_in[11];
    const float* W_hh      = (const float*)d_in[12];
    const float* b_ih      = (const float*)d_in[13];
    const float* b_hh      = (const float*)d_in[14];
    const float* W_out     = (const float*)d_in[15];
    const float* b_out     = (const float*)d_in[16];

    float* ws     = (float*)d_ws;
    float* whh2   = ws + WS_WHH2;
    float* rden   = ws + WS_RDEN;
    float* xlpart = ws + WS_XL;
    float* wsynum = ws + WS_YNUM;
    float* wsyden = ws + WS_YDEN;

    float* out     = (float*)d_out;
    float* out_yh  = out + 1;
    float* out_imp = out + 1 + BTOT;

    rits_den<<<dim3(T_LEN), dim3(1024), 0, stream>>>(masks, rden);
    rits_fold<<<dim3(256), dim3(256), 0, stream>>>(W_ih, W_hh, W_reg, whh2);

    rits_main<<<dim3(NB), dim3(NTHR), 0, stream>>>(
        values, masks, deltas, labels, is_train,
        W_decay, b_decay, W_reg, b_reg, W_ih, W_hh, b_ih, b_hh, W_out, b_out,
        whh2, rden, out_yh, out_imp, xlpart, wsynum, wsyden);

    rits_final<<<dim3(1), dim3(256), 0, stream>>>(xlpart, wsynum, wsyden, out);
}